// Round 3
// baseline (395.585 us; speedup 1.0000x reference)
//
#include <hip/hip_runtime.h>
#include <stdint.h>

// CodebookLayer (VQ snap): logits = x @ cb^T, argmax over 8192 codes, gather rows.
// R8: R7 hit 145us with MfmaUtil 43.7% -- per-tile budget shows the LDS pipe is
// now dominant (96 b128 reads + stage writes + conflicts ~ 1800 cyc vs MFMA
// 1100). Fix: load B fragments DIRECTLY from global (xq) into VGPRs -- the
// 32x32x64 B-fragment is 32 contiguous k-bytes per lane, and hi=0/hi=1 lanes of
// one column jointly cover a full 64B line per token row, so the gather is
// line-exact. This moves 32KB/tile from the saturated LDS pipe to the idle
// L2/VMEM pipe, halves LDS reads (64 b128), removes B stage-writes and B's
// bank conflicts. LDS = 4x16KB A-only buffers. K-loop fully unrolled: stage
// offsets and B addresses become immediates (near-zero loop VALU), wrap stages
// compile-time guarded out. vmcnt discipline: B loads first (compiler auto-
// waits their uses; draining them also drains the older stage(kt+1)), then
// stage(kt+2) behind a zero-cost asm memory fence; tile boundary = vmcnt(2) +
// s_barrier + fence -- never a full vmcnt(0) drain in the loop.

#define T_TOKENS 16384
#define N_CODES  8192
#define DIM      1024
#define BM 256                  // codes per block (M = codes)
#define BN 256                  // tokens per block
#define BK 64                   // K bytes per tile (fp8)
#define NBLK (N_CODES / BM)     // 32 code chunks
#define KITERS (DIM / BK)       // 16
#define EPS 13.0f
#define MAXCAND 48

typedef int   int8v  __attribute__((ext_vector_type(8)));
typedef int   int4v  __attribute__((ext_vector_type(4)));
typedef float f32x16 __attribute__((ext_vector_type(16)));

// async global->LDS, 16B per lane; LDS dest = wave-uniform base + lane*16
#define GLD16(gp, lp) \
  __builtin_amdgcn_global_load_lds((__attribute__((address_space(1))) void*)(gp), \
                                   (__attribute__((address_space(3))) void*)(lp), 16, 0, 0)

__device__ inline uint32_t umax(uint32_t a, uint32_t b) { return a > b ? a : b; }
__device__ inline uint32_t umin(uint32_t a, uint32_t b) { return a < b ? a : b; }
// compiler pattern-matches to v_med3_u32
__device__ inline uint32_t umed3(uint32_t a, uint32_t b, uint32_t c) {
  return umax(umin(a, b), umin(umax(a, b), c));
}

// monotone f32 -> u32 (larger float => larger uint)
__device__ inline uint32_t f32_key(float v) {
  int32_t b = (int32_t)__float_as_uint(v);
  return (uint32_t)(b ^ ((b >> 31) | (int32_t)0x80000000));
}
__device__ inline float key_f32(uint32_t u) {
  uint32_t b = (u & 0x80000000u) ? (u & 0x7FFFFFFFu) : ~u;
  return __uint_as_float(b);
}

// ------------------------------------------------------------------ prep (fused)
// blocks [0,16384): x (fp32) -> xq (fp8 e4m3); [16384,24576): cb -> cq
__global__ __launch_bounds__(256) void vq_prep(const float* __restrict__ x,
                                               const float* __restrict__ cbm,
                                               uint8_t* __restrict__ xq,
                                               uint8_t* __restrict__ cq) {
  size_t b = blockIdx.x;
  const float* src; uint8_t* dst;
  if (b < 16384) { src = x;  dst = xq; }
  else           { b -= 16384; src = cbm; dst = cq; }
  const size_t i = b * 256 + threadIdx.x;
  const float4 v = ((const float4*)src)[i];
  uint32_t r = __builtin_amdgcn_cvt_pk_fp8_f32(v.x, v.y, 0, false);
  r = __builtin_amdgcn_cvt_pk_fp8_f32(v.z, v.w, (int)r, true);
  ((uint32_t*)dst)[i] = r;
}

// ---------------------------------------------------------------- GEMM + top-3
#define MFMA8(A_, B_, C_) \
  __builtin_amdgcn_mfma_scale_f32_32x32x64_f8f6f4((A_), (B_), (C_), 0, 0, 0, \
                                                  0x7F7F7F7F, 0, 0x7F7F7F7F)

__global__ __launch_bounds__(512) void vq_gemm_top3(
    const uint8_t* __restrict__ cq,   // [C][D] fp8 (A operand)
    const uint8_t* __restrict__ xq,   // [T][D] fp8 (B operand)
    uint32_t* __restrict__ pk)        // [T][NBLK][3] packed keys
{
  // 4 A-only staging buffers of 16KB. Total 64KB.
  __shared__ uint8_t smem[4 * 16384];

  const int t    = threadIdx.x;
  const int wave = t >> 6;
  const int lane = t & 63;
  const int col  = lane & 31;
  const int hi   = lane >> 5;
  const int wm   = wave >> 2;          // 0..1: code half (128 codes)
  const int wn2  = (wave & 3) * 64;    // token offset within block

  // XCD-bijective swizzle over 2048 wgs (nwg%8==0): each XCD gets 4 code panels
  // x all 64 token panels -> cq panels stay L2-resident.
  const int f   = blockIdx.x;
  const int swz = (f & 7) * 256 + (f >> 3);
  const int cyi = swz >> 6;            // code chunk 0..31
  const int tb0 = (swz & 63) * BN;
  const int cb0 = cyi * BM;

  // A staging: per buffer 1024 chunks of 16B. Thread handles chunks {t, t+512}.
  // Dest is LINEAR (chunk c -> byte c*16); source k-chunk pre-swizzled: row r
  // stores source chunk j^((r>>1)&3) at slot j. Rows r and r+128 share perm.
  const int r0 = t >> 2;                                   // 0..127
  const int js = ((t & 3) ^ ((r0 >> 1) & 3)) * 16;
  const uint8_t* sA0 = cq + (size_t)(cb0 + r0) * DIM + js;
  const uint8_t* sA1 = cq + (size_t)(cb0 + r0 + 128) * DIM + js;

#define STAGE(bi, ti) do {                                     \
    uint8_t* Ad_ = smem + ((bi) << 14);                        \
    GLD16(sA0 + (ti) * BK, Ad_ + t * 16);                      \
    GLD16(sA1 + (ti) * BK, Ad_ + (t + 512) * 16);              \
  } while (0)

  // B direct-load pointers: lane (col,hi), frag j reads token row
  // tb0+wn2+j*32+col, k-bytes kt*64 + hi*32 .. +31 (2x dwordx4).
  const uint8_t* pB0 = xq + (size_t)(tb0 + wn2 + col) * DIM + hi * 32;
  const uint8_t* pB1 = pB0 + (size_t)32 * DIM;

  // A ds_read offsets: fragment row ra, source k-chunks {2*hi, 2*hi+1} at
  // slots XOR'd with perm(ra). Byte offsets within a 16KB buffer.
  const int j0 = hi * 2;
  int aoff[4][2];
#pragma unroll
  for (int mi = 0; mi < 4; ++mi) {
    const int ra = wm * 128 + mi * 32 + col;
    const int pa = (ra >> 1) & 3;
    aoff[mi][0] = ra * 64 + (j0 ^ pa) * 16;
    aoff[mi][1] = ra * 64 + ((j0 + 1) ^ pa) * 16;
  }

  // concat two 16B loads into one 32B fragment (no element-insert movs)
#define READ8(dst_, o0_, o1_) do {                                         \
    const int4v lo_ = *(const int4v*)(cur + (o0_));                        \
    const int4v hq_ = *(const int4v*)(cur + (o1_));                        \
    dst_ = __builtin_shufflevector(lo_, hq_, 0, 1, 2, 3, 4, 5, 6, 7);      \
  } while (0)

  f32x16 acc[4][2];
#pragma unroll
  for (int i = 0; i < 4; ++i)
#pragma unroll
    for (int j = 0; j < 2; ++j)
#pragma unroll
      for (int r = 0; r < 16; ++r) acc[i][j][r] = 0.f;

  // prologue: A tiles 0,1 in flight (4 vmem ops/thread)
  STAGE(0, 0);
  STAGE(1, 1);

#pragma unroll
  for (int kt = 0; kt < KITERS; ++kt) {
    // tile boundary: counted wait. Outstanding (steady state): stage(kt+1)'s
    // 2 loads (newest). vmcnt(2) guarantees stage(kt) and older all landed.
    // Barrier globalizes; trailing zero-cost fence pins memory ops below the
    // barrier (raw s_barrier builtin has no memory-ordering semantics).
    asm volatile("s_waitcnt vmcnt(2)" ::: "memory");
    __builtin_amdgcn_s_barrier();
    asm volatile("" ::: "memory");

    const uint8_t* cur = smem + ((kt & 3) << 14);

    // B fragments straight from L2. Issued FIRST: the compiler's auto-wait on
    // their uses (before the MFMAs) then also drains the older stage(kt+1),
    // which is exactly the readiness the next tile's vmcnt(2) assumes.
    int8v b0, b1;
    {
      const int4v l0 = *(const int4v*)(pB0 + kt * BK);
      const int4v h0 = *(const int4v*)(pB0 + kt * BK + 16);
      const int4v l1 = *(const int4v*)(pB1 + kt * BK);
      const int4v h1 = *(const int4v*)(pB1 + kt * BK + 16);
      b0 = __builtin_shufflevector(l0, h0, 0, 1, 2, 3, 4, 5, 6, 7);
      b1 = __builtin_shufflevector(l1, h1, 0, 1, 2, 3, 4, 5, 6, 7);
    }
    asm volatile("" ::: "memory");   // keep stage VMEM *after* B VMEM in order

    // stage tile kt+2 two tiles ahead (compile-time guarded: no wrap stages)
    if (kt < KITERS - 2) STAGE((kt + 2) & 3, kt + 2);

    // 8 ds_read_b128 (A) + 8 MFMA, compiler-scheduled: partial lgkmcnt waits
    // let MFMAs start as fragments land; 2 waves/SIMD drift within the tile.
    int8v a[4];
#pragma unroll
    for (int mi = 0; mi < 4; ++mi) READ8(a[mi], aoff[mi][0], aoff[mi][1]);

    acc[0][0] = MFMA8(a[0], b0, acc[0][0]);
    acc[1][0] = MFMA8(a[1], b0, acc[1][0]);
    acc[0][1] = MFMA8(a[0], b1, acc[0][1]);
    acc[1][1] = MFMA8(a[1], b1, acc[1][1]);
    acc[2][0] = MFMA8(a[2], b0, acc[2][0]);
    acc[3][0] = MFMA8(a[3], b0, acc[3][0]);
    acc[2][1] = MFMA8(a[2], b1, acc[2][1]);
    acc[3][1] = MFMA8(a[3], b1, acc[3][1]);
  }
  __syncthreads();   // full drain before smem reuse

  // Epilogue: per-token top-3 over this block's 256 codes.
  // C/D 32x32 layout: col(token)=lane&31, row(code)=(reg&3)+8*(reg>>2)+4*(lane>>5).
  // key = (monotone(value) & ~0xFF) | (255 - code_in_block).
  uint32_t* cand = (uint32_t*)smem;  // [256 tokens][2 halves][3] = 6KB
  const int invb = 255 - wm * 128 - 4 * hi;
#pragma unroll
  for (int j = 0; j < 2; ++j) {
    uint32_t K1 = 0, K2 = 0, K3 = 0;
#pragma unroll
    for (int mi = 0; mi < 4; ++mi) {
#pragma unroll
      for (int rg = 0; rg < 16; ++rg) {
        const int rowoff = (rg & 3) + 8 * (rg >> 2);
        const uint32_t key = (f32_key(acc[mi][j][rg]) & 0xFFFFFF00u)
                           | (uint32_t)(invb - mi * 32 - rowoff);
        const uint32_t t3 = umed3(key, K2, K3);
        const uint32_t t2 = umed3(key, K1, K2);
        K1 = umax(key, K1); K2 = t2; K3 = t3;
      }
    }
    // merge row-halves (lane ^ 32 holds same token, other 4-row offset)
    const uint32_t o1 = __shfl_xor(K1, 32, 64);
    const uint32_t o2 = __shfl_xor(K2, 32, 64);
    const uint32_t o3 = __shfl_xor(K3, 32, 64);
    const uint32_t m1 = umin(K1, o1), M2 = umax(K2, o2);
    const uint32_t m2 = umin(K2, o2), M3 = umax(K3, o3);
    K1 = umax(K1, o1);
    const uint32_t nk2 = umax(m1, M2);
    K3 = umax(umax(m2, umin(m1, M2)), M3);
    K2 = nk2;
    if (hi == 0) {
      uint32_t* c = &cand[((wn2 + j * 32 + col) * 2 + wm) * 3];
      c[0] = K1; c[1] = K2; c[2] = K3;
    }
  }
  __syncthreads();
  if (t < BN) {
    const uint32_t a1 = cand[(t * 2 + 0) * 3 + 0], a2 = cand[(t * 2 + 0) * 3 + 1],
                   a3 = cand[(t * 2 + 0) * 3 + 2];
    const uint32_t b1k = cand[(t * 2 + 1) * 3 + 0], b2 = cand[(t * 2 + 1) * 3 + 1],
                   b3 = cand[(t * 2 + 1) * 3 + 2];
    const uint32_t m1 = umin(a1, b1k), M2 = umax(a2, b2);
    const uint32_t m2 = umin(a2, b2), M3 = umax(a3, b3);
    uint32_t* dst = pk + ((size_t)(tb0 + t) * NBLK + cyi) * 3;
    dst[0] = umax(a1, b1k);
    dst[1] = umax(m1, M2);
    dst[2] = umax(umax(m2, umin(m1, M2)), M3);
  }
#undef STAGE
#undef READ8
}

// ------------------------------------------- reduce + fp64 recheck + gather
__global__ __launch_bounds__(256) void vq_reduce_gather(
    const uint32_t* __restrict__ pk, const float* __restrict__ x,
    const float* __restrict__ cb, float* __restrict__ out)
{
  __shared__ float xs[DIM];
  __shared__ uint32_t wmax[4];
  __shared__ int scand[MAXCAND];
  __shared__ int scnt;
  __shared__ double sdot[MAXCAND];
  __shared__ int sbesti;

  const int tkn = blockIdx.x, t = threadIdx.x, lane = t & 63, wv = t >> 6;
  ((float4*)xs)[t] = ((const float4*)(x + (size_t)tkn * DIM))[t];
  const uint32_t key = (t < 3 * NBLK) ? pk[(size_t)tkn * (3 * NBLK) + t] : 0u;
  uint32_t m = key;
#pragma unroll
  for (int d = 1; d < 64; d <<= 1) m = umax(m, __shfl_xor(m, d, 64));
  if (t == 0) scnt = 0;
  if (lane == 0) wmax[wv] = m;
  __syncthreads();
  const float Mv = key_f32(umax(umax(wmax[0], wmax[1]), umax(wmax[2], wmax[3])));
  if (t < 3 * NBLK && key_f32(key) >= Mv - EPS) {
    const int p = atomicAdd(&scnt, 1);
    if (p < MAXCAND) scand[p] = (t / 3) * BM + 255 - (int)(key & 255u);
  }
  __syncthreads();
  const int cnt = scnt < MAXCAND ? scnt : MAXCAND;

  if (cnt > 1) {
    // wave-parallel: wave wv handles candidates wv, wv+4, ...
    for (int k = wv; k < cnt; k += 4) {
      const int c = scand[k];
      const float* cr = cb + (size_t)c * DIM;
      double s = 0.0;
#pragma unroll
      for (int q = 0; q < 4; ++q) {
        const float4 xv = ((const float4*)xs)[lane + 64 * q];
        const float4 cv = ((const float4*)cr)[lane + 64 * q];
        s += (double)xv.x * cv.x + (double)xv.y * cv.y
           + (double)xv.z * cv.z + (double)xv.w * cv.w;
      }
#pragma unroll
      for (int d = 1; d < 64; d <<= 1) s += __shfl_xor(s, d, 64);
      if (lane == 0) sdot[k] = s;
    }
    __syncthreads();
    if (t == 0) {
      double best = -1e300; int bi = N_CODES;
      for (int k = 0; k < cnt; ++k) {
        const int c = scand[k];
        if (sdot[k] > best || (sdot[k] == best && c < bi)) { best = sdot[k]; bi = c; }
      }
      sbesti = bi;
    }
  } else {
    if (t == 0) sbesti = scand[0];
  }
  __syncthreads();
  const int code = sbesti;
  ((float4*)(out + (size_t)tkn * DIM))[t] = ((const float4*)(cb + (size_t)code * DIM))[t];
}

// ------------------------------------------------- fallback (ws too small)
__global__ __launch_bounds__(256) void vq_naive(const float* __restrict__ x,
                                                const float* __restrict__ cb,
                                                float* __restrict__ out) {
  __shared__ float xs[DIM];
  __shared__ float bv[256];
  __shared__ int   bix[256];
  const int tkn = blockIdx.x;
  const int t = threadIdx.x;
  for (int d = t; d < DIM; d += 256) xs[d] = x[(size_t)tkn * DIM + d];
  __syncthreads();
  float best = -1e30f; int bi = N_CODES;
  for (int c = t; c < N_CODES; c += 256) {
    const float* cr = cb + (size_t)c * DIM;
    float s = 0.f;
    for (int d = 0; d < DIM; ++d) s += xs[d] * cr[d];
    if (s > best || (s == best && c < bi)) { best = s; bi = c; }
  }
  bv[t] = best; bix[t] = bi;
  __syncthreads();
  for (int off = 128; off > 0; off >>= 1) {
    if (t < off) {
      if (bv[t + off] > bv[t] || (bv[t + off] == bv[t] && bix[t + off] < bix[t])) {
        bv[t] = bv[t + off]; bix[t] = bix[t + off];
      }
    }
    __syncthreads();
  }
  const int code = bix[0];
  for (int d = t; d < DIM; d += 256)
    out[(size_t)tkn * DIM + d] = cb[(size_t)code * DIM + d];
}

// ---------------------------------------------------------------------- launch
extern "C" void kernel_launch(void* const* d_in, const int* in_sizes, int n_in,
                              void* d_out, int out_size, void* d_ws, size_t ws_size,
                              hipStream_t stream) {
  const float* x  = (const float*)d_in[0];   // [16384][1024]
  const float* cb = (const float*)d_in[1];   // [8192][1024]
  float* out = (float*)d_out;

  const size_t MB = 1024 * 1024;
  const size_t need = 24 * MB + (size_t)T_TOKENS * NBLK * 3 * 4;  // ~30.3MB
  if (ws_size >= need) {
    uint8_t*  xq = (uint8_t*)d_ws;             // 16MB fp8 tokens
    uint8_t*  cq = xq + 16 * MB;               // 8MB  fp8 codebook
    uint32_t* pk = (uint32_t*)(cq + 8 * MB);   // 6.3MB packed keys

    vq_prep<<<dim3(24576), 256, 0, stream>>>(x, cb, xq, cq);
    vq_gemm_top3<<<dim3((T_TOKENS / BN) * (N_CODES / BM)), 512, 0, stream>>>(cq, xq, pk);
    vq_reduce_gather<<<dim3(T_TOKENS), 256, 0, stream>>>(pk, x, cb, out);
  } else {
    vq_naive<<<dim3(T_TOKENS), 256, 0, stream>>>(x, cb, out);
  }
}

// Round 4
// 380.857 us; speedup vs baseline: 1.0387x; 1.0387x over previous
//
#include <hip/hip_runtime.h>
#include <stdint.h>

// CodebookLayer (VQ snap): logits = x @ cb^T, argmax over 8192 codes, gather rows.
// R9: R8 (B direct-from-global) was right about relieving LDS (conflicts
// 1.27e7 -> 8.5e6) but exposed B's L2 latency on the critical path: B loads
// were issued and consumed in the SAME tile, so the compiler's vmcnt wait for
// the B registers stalled every tile (~+1475 cyc/tile, MfmaUtil 43.7 -> 25.5).
// Fix: software-pipeline B ONE TILE AHEAD in registers (double-buffered pair,
// rotated by SSA-rename in the fully-unrolled loop). B(kt) is ~1600+ cyc old
// when its MFMAs fire -- latency fully hidden. vmcnt discipline (in-order
// completion): boundary = vmcnt(6) steady (B(kt) 4 + stage(kt+1) 2
// outstanding), vmcnt(4) at the last tile; never drained to 0 in the loop.

#define T_TOKENS 16384
#define N_CODES  8192
#define DIM      1024
#define BM 256                  // codes per block (M = codes)
#define BN 256                  // tokens per block
#define BK 64                   // K bytes per tile (fp8)
#define NBLK (N_CODES / BM)     // 32 code chunks
#define KITERS (DIM / BK)       // 16
#define EPS 13.0f
#define MAXCAND 48

typedef int   int8v  __attribute__((ext_vector_type(8)));
typedef int   int4v  __attribute__((ext_vector_type(4)));
typedef float f32x16 __attribute__((ext_vector_type(16)));

// async global->LDS, 16B per lane; LDS dest = wave-uniform base + lane*16
#define GLD16(gp, lp) \
  __builtin_amdgcn_global_load_lds((__attribute__((address_space(1))) void*)(gp), \
                                   (__attribute__((address_space(3))) void*)(lp), 16, 0, 0)

__device__ inline uint32_t umax(uint32_t a, uint32_t b) { return a > b ? a : b; }
__device__ inline uint32_t umin(uint32_t a, uint32_t b) { return a < b ? a : b; }
// compiler pattern-matches to v_med3_u32
__device__ inline uint32_t umed3(uint32_t a, uint32_t b, uint32_t c) {
  return umax(umin(a, b), umin(umax(a, b), c));
}

// monotone f32 -> u32 (larger float => larger uint)
__device__ inline uint32_t f32_key(float v) {
  int32_t b = (int32_t)__float_as_uint(v);
  return (uint32_t)(b ^ ((b >> 31) | (int32_t)0x80000000));
}
__device__ inline float key_f32(uint32_t u) {
  uint32_t b = (u & 0x80000000u) ? (u & 0x7FFFFFFFu) : ~u;
  return __uint_as_float(b);
}

// ------------------------------------------------------------------ prep (fused)
// blocks [0,16384): x (fp32) -> xq (fp8 e4m3); [16384,24576): cb -> cq
__global__ __launch_bounds__(256) void vq_prep(const float* __restrict__ x,
                                               const float* __restrict__ cbm,
                                               uint8_t* __restrict__ xq,
                                               uint8_t* __restrict__ cq) {
  size_t b = blockIdx.x;
  const float* src; uint8_t* dst;
  if (b < 16384) { src = x;  dst = xq; }
  else           { b -= 16384; src = cbm; dst = cq; }
  const size_t i = b * 256 + threadIdx.x;
  const float4 v = ((const float4*)src)[i];
  uint32_t r = __builtin_amdgcn_cvt_pk_fp8_f32(v.x, v.y, 0, false);
  r = __builtin_amdgcn_cvt_pk_fp8_f32(v.z, v.w, (int)r, true);
  ((uint32_t*)dst)[i] = r;
}

// ---------------------------------------------------------------- GEMM + top-3
#define MFMA8(A_, B_, C_) \
  __builtin_amdgcn_mfma_scale_f32_32x32x64_f8f6f4((A_), (B_), (C_), 0, 0, 0, \
                                                  0x7F7F7F7F, 0, 0x7F7F7F7F)

__global__ __launch_bounds__(512) void vq_gemm_top3(
    const uint8_t* __restrict__ cq,   // [C][D] fp8 (A operand)
    const uint8_t* __restrict__ xq,   // [T][D] fp8 (B operand)
    uint32_t* __restrict__ pk)        // [T][NBLK][3] packed keys
{
  // 4 A-only staging buffers of 16KB. Total 64KB.
  __shared__ uint8_t smem[4 * 16384];

  const int t    = threadIdx.x;
  const int wave = t >> 6;
  const int lane = t & 63;
  const int col  = lane & 31;
  const int hi   = lane >> 5;
  const int wm   = wave >> 2;          // 0..1: code half (128 codes)
  const int wn2  = (wave & 3) * 64;    // token offset within block

  // XCD-bijective swizzle over 2048 wgs (nwg%8==0): each XCD gets 4 code panels
  // x all 64 token panels -> cq panels stay L2-resident.
  const int f   = blockIdx.x;
  const int swz = (f & 7) * 256 + (f >> 3);
  const int cyi = swz >> 6;            // code chunk 0..31
  const int tb0 = (swz & 63) * BN;
  const int cb0 = cyi * BM;

  // A staging: per buffer 1024 chunks of 16B. Thread handles chunks {t, t+512}.
  // Dest is LINEAR (chunk c -> byte c*16); source k-chunk pre-swizzled: row r
  // stores source chunk j^((r>>1)&3) at slot j. Rows r and r+128 share perm.
  const int r0 = t >> 2;                                   // 0..127
  const int js = ((t & 3) ^ ((r0 >> 1) & 3)) * 16;
  const uint8_t* sA0 = cq + (size_t)(cb0 + r0) * DIM + js;
  const uint8_t* sA1 = cq + (size_t)(cb0 + r0 + 128) * DIM + js;

#define STAGE(bi, ti) do {                                     \
    uint8_t* Ad_ = smem + ((bi) << 14);                        \
    GLD16(sA0 + (ti) * BK, Ad_ + t * 16);                      \
    GLD16(sA1 + (ti) * BK, Ad_ + (t + 512) * 16);              \
  } while (0)

  // B direct-load pointers: lane (col,hi), frag j reads token row
  // tb0+wn2+j*32+col, k-bytes kt*64 + hi*32 .. +31 (2x dwordx4).
  const uint8_t* pB0 = xq + (size_t)(tb0 + wn2 + col) * DIM + hi * 32;
  const uint8_t* pB1 = pB0 + (size_t)32 * DIM;

#define LOADB(d0_, d1_, ti_) do {                                   \
    const int4v l0_ = *(const int4v*)(pB0 + (ti_) * BK);            \
    const int4v h0_ = *(const int4v*)(pB0 + (ti_) * BK + 16);       \
    const int4v l1_ = *(const int4v*)(pB1 + (ti_) * BK);            \
    const int4v h1_ = *(const int4v*)(pB1 + (ti_) * BK + 16);       \
    d0_ = __builtin_shufflevector(l0_, h0_, 0, 1, 2, 3, 4, 5, 6, 7); \
    d1_ = __builtin_shufflevector(l1_, h1_, 0, 1, 2, 3, 4, 5, 6, 7); \
  } while (0)

  // A ds_read offsets: fragment row ra, source k-chunks {2*hi, 2*hi+1} at
  // slots XOR'd with perm(ra). Byte offsets within a 16KB buffer.
  const int j0 = hi * 2;
  int aoff[4][2];
#pragma unroll
  for (int mi = 0; mi < 4; ++mi) {
    const int ra = wm * 128 + mi * 32 + col;
    const int pa = (ra >> 1) & 3;
    aoff[mi][0] = ra * 64 + (j0 ^ pa) * 16;
    aoff[mi][1] = ra * 64 + ((j0 + 1) ^ pa) * 16;
  }

  // concat two 16B loads into one 32B fragment (no element-insert movs)
#define READ8(dst_, o0_, o1_) do {                                         \
    const int4v lo_ = *(const int4v*)(cur + (o0_));                        \
    const int4v hq_ = *(const int4v*)(cur + (o1_));                        \
    dst_ = __builtin_shufflevector(lo_, hq_, 0, 1, 2, 3, 4, 5, 6, 7);      \
  } while (0)

  f32x16 acc[4][2];
#pragma unroll
  for (int i = 0; i < 4; ++i)
#pragma unroll
    for (int j = 0; j < 2; ++j)
#pragma unroll
      for (int r = 0; r < 16; ++r) acc[i][j][r] = 0.f;

  // prologue: A tiles 0,1 staged (4 GLDs), B tile 0 in regs (4 loads).
  // Outstanding entering tile 0: stage0(2), stage1(2), B0(4) = 8.
  STAGE(0, 0);
  STAGE(1, 1);
  int8v bc0, bc1, bn0, bn1;
  LOADB(bc0, bc1, 0);

#pragma unroll
  for (int kt = 0; kt < KITERS; ++kt) {
    // tile boundary (in-order vmcnt completion): steady-state outstanding =
    // B(kt)(4, issued last tile) + stage(kt+1)(2) = 6; ops issued after
    // stage(kt) = exactly those 6 -> vmcnt(6) guarantees stage(kt) landed
    // without draining the newer prefetches. Last tile: only B(15)(4) is
    // newer than stage(15) -> vmcnt(4).
    if (kt == KITERS - 1) asm volatile("s_waitcnt vmcnt(4)" ::: "memory");
    else                  asm volatile("s_waitcnt vmcnt(6)" ::: "memory");
    __builtin_amdgcn_s_barrier();
    __builtin_amdgcn_sched_barrier(0);

    const uint8_t* cur = smem + ((kt & 3) << 14);

    // prefetch B(kt+1) into the shadow pair -- consumed NEXT tile, so its
    // L2 latency hides under this tile's MFMAs.
    if (kt < KITERS - 1) LOADB(bn0, bn1, kt + 1);
    asm volatile("" ::: "memory");   // keep stage VMEM after B VMEM in order

    // stage tile kt+2 two tiles ahead (compile-time guarded: no wrap stages)
    if (kt < KITERS - 2) STAGE((kt + 2) & 3, kt + 2);

    // 8 ds_read_b128 (A) + 8 MFMA, compiler-scheduled: partial lgkmcnt waits
    // let MFMAs start as fragments land; 2 waves/SIMD drift within the tile.
    int8v a[4];
#pragma unroll
    for (int mi = 0; mi < 4; ++mi) READ8(a[mi], aoff[mi][0], aoff[mi][1]);

    acc[0][0] = MFMA8(a[0], bc0, acc[0][0]);
    acc[1][0] = MFMA8(a[1], bc0, acc[1][0]);
    acc[0][1] = MFMA8(a[0], bc1, acc[0][1]);
    acc[1][1] = MFMA8(a[1], bc1, acc[1][1]);
    acc[2][0] = MFMA8(a[2], bc0, acc[2][0]);
    acc[3][0] = MFMA8(a[3], bc0, acc[3][0]);
    acc[2][1] = MFMA8(a[2], bc1, acc[2][1]);
    acc[3][1] = MFMA8(a[3], bc1, acc[3][1]);

    // rotate B double-buffer (SSA-renamed in unrolled code, no v_movs)
    bc0 = bn0; bc1 = bn1;
  }
  __syncthreads();   // full drain before smem reuse

  // Epilogue: per-token top-3 over this block's 256 codes.
  // C/D 32x32 layout: col(token)=lane&31, row(code)=(reg&3)+8*(reg>>2)+4*(lane>>5).
  // key = (monotone(value) & ~0xFF) | (255 - code_in_block).
  uint32_t* cand = (uint32_t*)smem;  // [256 tokens][2 halves][3] = 6KB
  const int invb = 255 - wm * 128 - 4 * hi;
#pragma unroll
  for (int j = 0; j < 2; ++j) {
    uint32_t K1 = 0, K2 = 0, K3 = 0;
#pragma unroll
    for (int mi = 0; mi < 4; ++mi) {
#pragma unroll
      for (int rg = 0; rg < 16; ++rg) {
        const int rowoff = (rg & 3) + 8 * (rg >> 2);
        const uint32_t key = (f32_key(acc[mi][j][rg]) & 0xFFFFFF00u)
                           | (uint32_t)(invb - mi * 32 - rowoff);
        const uint32_t t3 = umed3(key, K2, K3);
        const uint32_t t2 = umed3(key, K1, K2);
        K1 = umax(key, K1); K2 = t2; K3 = t3;
      }
    }
    // merge row-halves (lane ^ 32 holds same token, other 4-row offset)
    const uint32_t o1 = __shfl_xor(K1, 32, 64);
    const uint32_t o2 = __shfl_xor(K2, 32, 64);
    const uint32_t o3 = __shfl_xor(K3, 32, 64);
    const uint32_t m1 = umin(K1, o1), M2 = umax(K2, o2);
    const uint32_t m2 = umin(K2, o2), M3 = umax(K3, o3);
    K1 = umax(K1, o1);
    const uint32_t nk2 = umax(m1, M2);
    K3 = umax(umax(m2, umin(m1, M2)), M3);
    K2 = nk2;
    if (hi == 0) {
      uint32_t* c = &cand[((wn2 + j * 32 + col) * 2 + wm) * 3];
      c[0] = K1; c[1] = K2; c[2] = K3;
    }
  }
  __syncthreads();
  if (t < BN) {
    const uint32_t a1 = cand[(t * 2 + 0) * 3 + 0], a2 = cand[(t * 2 + 0) * 3 + 1],
                   a3 = cand[(t * 2 + 0) * 3 + 2];
    const uint32_t b1k = cand[(t * 2 + 1) * 3 + 0], b2 = cand[(t * 2 + 1) * 3 + 1],
                   b3 = cand[(t * 2 + 1) * 3 + 2];
    const uint32_t m1 = umin(a1, b1k), M2 = umax(a2, b2);
    const uint32_t m2 = umin(a2, b2), M3 = umax(a3, b3);
    uint32_t* dst = pk + ((size_t)(tb0 + t) * NBLK + cyi) * 3;
    dst[0] = umax(a1, b1k);
    dst[1] = umax(m1, M2);
    dst[2] = umax(umax(m2, umin(m1, M2)), M3);
  }
#undef STAGE
#undef LOADB
#undef READ8
}

// ------------------------------------------- reduce + fp64 recheck + gather
__global__ __launch_bounds__(256) void vq_reduce_gather(
    const uint32_t* __restrict__ pk, const float* __restrict__ x,
    const float* __restrict__ cb, float* __restrict__ out)
{
  __shared__ float xs[DIM];
  __shared__ uint32_t wmax[4];
  __shared__ int scand[MAXCAND];
  __shared__ int scnt;
  __shared__ double sdot[MAXCAND];
  __shared__ int sbesti;

  const int tkn = blockIdx.x, t = threadIdx.x, lane = t & 63, wv = t >> 6;
  ((float4*)xs)[t] = ((const float4*)(x + (size_t)tkn * DIM))[t];
  const uint32_t key = (t < 3 * NBLK) ? pk[(size_t)tkn * (3 * NBLK) + t] : 0u;
  uint32_t m = key;
#pragma unroll
  for (int d = 1; d < 64; d <<= 1) m = umax(m, __shfl_xor(m, d, 64));
  if (t == 0) scnt = 0;
  if (lane == 0) wmax[wv] = m;
  __syncthreads();
  const float Mv = key_f32(umax(umax(wmax[0], wmax[1]), umax(wmax[2], wmax[3])));
  if (t < 3 * NBLK && key_f32(key) >= Mv - EPS) {
    const int p = atomicAdd(&scnt, 1);
    if (p < MAXCAND) scand[p] = (t / 3) * BM + 255 - (int)(key & 255u);
  }
  __syncthreads();
  const int cnt = scnt < MAXCAND ? scnt : MAXCAND;

  if (cnt > 1) {
    // wave-parallel: wave wv handles candidates wv, wv+4, ...
    for (int k = wv; k < cnt; k += 4) {
      const int c = scand[k];
      const float* cr = cb + (size_t)c * DIM;
      double s = 0.0;
#pragma unroll
      for (int q = 0; q < 4; ++q) {
        const float4 xv = ((const float4*)xs)[lane + 64 * q];
        const float4 cv = ((const float4*)cr)[lane + 64 * q];
        s += (double)xv.x * cv.x + (double)xv.y * cv.y
           + (double)xv.z * cv.z + (double)xv.w * cv.w;
      }
#pragma unroll
      for (int d = 1; d < 64; d <<= 1) s += __shfl_xor(s, d, 64);
      if (lane == 0) sdot[k] = s;
    }
    __syncthreads();
    if (t == 0) {
      double best = -1e300; int bi = N_CODES;
      for (int k = 0; k < cnt; ++k) {
        const int c = scand[k];
        if (sdot[k] > best || (sdot[k] == best && c < bi)) { best = sdot[k]; bi = c; }
      }
      sbesti = bi;
    }
  } else {
    if (t == 0) sbesti = scand[0];
  }
  __syncthreads();
  const int code = sbesti;
  ((float4*)(out + (size_t)tkn * DIM))[t] = ((const float4*)(cb + (size_t)code * DIM))[t];
}

// ------------------------------------------------- fallback (ws too small)
__global__ __launch_bounds__(256) void vq_naive(const float* __restrict__ x,
                                                const float* __restrict__ cb,
                                                float* __restrict__ out) {
  __shared__ float xs[DIM];
  __shared__ float bv[256];
  __shared__ int   bix[256];
  const int tkn = blockIdx.x;
  const int t = threadIdx.x;
  for (int d = t; d < DIM; d += 256) xs[d] = x[(size_t)tkn * DIM + d];
  __syncthreads();
  float best = -1e30f; int bi = N_CODES;
  for (int c = t; c < N_CODES; c += 256) {
    const float* cr = cb + (size_t)c * DIM;
    float s = 0.f;
    for (int d = 0; d < DIM; ++d) s += xs[d] * cr[d];
    if (s > best || (s == best && c < bi)) { best = s; bi = c; }
  }
  bv[t] = best; bix[t] = bi;
  __syncthreads();
  for (int off = 128; off > 0; off >>= 1) {
    if (t < off) {
      if (bv[t + off] > bv[t] || (bv[t + off] == bv[t] && bix[t + off] < bix[t])) {
        bv[t] = bv[t + off]; bix[t] = bix[t + off];
      }
    }
    __syncthreads();
  }
  const int code = bix[0];
  for (int d = t; d < DIM; d += 256)
    out[(size_t)tkn * DIM + d] = cb[(size_t)code * DIM + d];
}

// ---------------------------------------------------------------------- launch
extern "C" void kernel_launch(void* const* d_in, const int* in_sizes, int n_in,
                              void* d_out, int out_size, void* d_ws, size_t ws_size,
                              hipStream_t stream) {
  const float* x  = (const float*)d_in[0];   // [16384][1024]
  const float* cb = (const float*)d_in[1];   // [8192][1024]
  float* out = (float*)d_out;

  const size_t MB = 1024 * 1024;
  const size_t need = 24 * MB + (size_t)T_TOKENS * NBLK * 3 * 4;  // ~30.3MB
  if (ws_size >= need) {
    uint8_t*  xq = (uint8_t*)d_ws;             // 16MB fp8 tokens
    uint8_t*  cq = xq + 16 * MB;               // 8MB  fp8 codebook
    uint32_t* pk = (uint32_t*)(cq + 8 * MB);   // 6.3MB packed keys

    vq_prep<<<dim3(24576), 256, 0, stream>>>(x, cb, xq, cq);
    vq_gemm_top3<<<dim3((T_TOKENS / BN) * (N_CODES / BM)), 512, 0, stream>>>(cq, xq, pk);
    vq_reduce_gather<<<dim3(T_TOKENS), 256, 0, stream>>>(pk, x, cb, out);
  } else {
    vq_naive<<<dim3(T_TOKENS), 256, 0, stream>>>(x, cb, out);
  }
}

// Round 5
// 340.594 us; speedup vs baseline: 1.1615x; 1.1182x over previous
//
#include <hip/hip_runtime.h>
#include <stdint.h>

// CodebookLayer (VQ snap): logits = x @ cb^T, argmax over 8192 codes, gather rows.
// R10: R8/R9 proved direct-global B is throughput-limited (32-line stride-1024
// gather, L2-miss: full-tile prefetch recovered only 13us) -- B goes back to
// LDS (R7 structure, 145us / MfmaUtil 43.7%). R7's limiter was the LDS pipe:
// 8 waves x (128x64) read 96KB/tile (A x4 dup, B x2) vs MFMA 1100 cyc. Fix the
// DUPLICATION: 4 waves x (128x128) wave tiles (same 256x256 block, 256 thr)
// read only 64KB/tile (A x2, B x2) -> LDS ~1290 cyc ~ MFMA 1100 -> MFMA-bound
// if overlapped. acc = 4x4 x f32x16 = 256 regs + operands ~ 330 < 512 unified
// file, __launch_bounds__(256,1). Staging: depth-2 counted vmcnt(8) boundary
// (never 0 mid-loop), proven (row>>1)&3 chunk swizzle, linear GLD dest.

#define T_TOKENS 16384
#define N_CODES  8192
#define DIM      1024
#define BM 256                  // codes per block (M = codes)
#define BN 256                  // tokens per block
#define BK 64                   // K bytes per tile (fp8)
#define NBLK (N_CODES / BM)     // 32 code chunks
#define KITERS (DIM / BK)       // 16
#define EPS 13.0f
#define MAXCAND 48

typedef int   int8v  __attribute__((ext_vector_type(8)));
typedef int   int4v  __attribute__((ext_vector_type(4)));
typedef float f32x16 __attribute__((ext_vector_type(16)));

// async global->LDS, 16B per lane; LDS dest = wave-uniform base + lane*16
#define GLD16(gp, lp) \
  __builtin_amdgcn_global_load_lds((__attribute__((address_space(1))) void*)(gp), \
                                   (__attribute__((address_space(3))) void*)(lp), 16, 0, 0)

__device__ inline uint32_t umax(uint32_t a, uint32_t b) { return a > b ? a : b; }
__device__ inline uint32_t umin(uint32_t a, uint32_t b) { return a < b ? a : b; }
// compiler pattern-matches to v_med3_u32
__device__ inline uint32_t umed3(uint32_t a, uint32_t b, uint32_t c) {
  return umax(umin(a, b), umin(umax(a, b), c));
}

// monotone f32 -> u32 (larger float => larger uint)
__device__ inline uint32_t f32_key(float v) {
  int32_t b = (int32_t)__float_as_uint(v);
  return (uint32_t)(b ^ ((b >> 31) | (int32_t)0x80000000));
}
__device__ inline float key_f32(uint32_t u) {
  uint32_t b = (u & 0x80000000u) ? (u & 0x7FFFFFFFu) : ~u;
  return __uint_as_float(b);
}

// ------------------------------------------------------------------ prep (fused)
// blocks [0,16384): x (fp32) -> xq (fp8 e4m3); [16384,24576): cb -> cq
__global__ __launch_bounds__(256) void vq_prep(const float* __restrict__ x,
                                               const float* __restrict__ cbm,
                                               uint8_t* __restrict__ xq,
                                               uint8_t* __restrict__ cq) {
  size_t b = blockIdx.x;
  const float* src; uint8_t* dst;
  if (b < 16384) { src = x;  dst = xq; }
  else           { b -= 16384; src = cbm; dst = cq; }
  const size_t i = b * 256 + threadIdx.x;
  const float4 v = ((const float4*)src)[i];
  uint32_t r = __builtin_amdgcn_cvt_pk_fp8_f32(v.x, v.y, 0, false);
  r = __builtin_amdgcn_cvt_pk_fp8_f32(v.z, v.w, (int)r, true);
  ((uint32_t*)dst)[i] = r;
}

// ---------------------------------------------------------------- GEMM + top-3
#define MFMA8(A_, B_, C_) \
  __builtin_amdgcn_mfma_scale_f32_32x32x64_f8f6f4((A_), (B_), (C_), 0, 0, 0, \
                                                  0x7F7F7F7F, 0, 0x7F7F7F7F)

__global__ __launch_bounds__(256, 1) void vq_gemm_top3(
    const uint8_t* __restrict__ cq,   // [C][D] fp8 (A operand)
    const uint8_t* __restrict__ xq,   // [T][D] fp8 (B operand)
    uint32_t* __restrict__ pk)        // [T][NBLK][3] packed keys
{
  // 4 staging buffers of 32KB: A(16KB) | B(16KB). Total 128KB.
  __shared__ uint8_t smem[4 * 32768];

  const int t    = threadIdx.x;
  const int wave = t >> 6;             // 0..3
  const int lane = t & 63;
  const int col  = lane & 31;
  const int hi   = lane >> 5;
  const int wm   = wave >> 1;          // 0..1: code half (128 codes)
  const int wn   = wave & 1;           // 0..1: token half (128 tokens)

  // XCD-bijective swizzle over 2048 wgs (nwg%8==0): each XCD gets 4 code panels
  // x all 64 token panels -> cq panels stay L2-resident.
  const int f   = blockIdx.x;
  const int swz = (f & 7) * 256 + (f >> 3);
  const int cyi = swz >> 6;            // code chunk 0..31
  const int tb0 = (swz & 63) * BN;
  const int cb0 = cyi * BM;

  // Staging: per buffer A 1024 + B 1024 chunks of 16B. Thread handles chunks
  // {t + 256q}, q=0..3, of each. Dest LINEAR (chunk c -> byte c*16); source
  // k-chunk pre-swizzled: row r stores source chunk j^((r>>1)&3) at slot j.
  // Rows r and r+64q share the perm ((r>>1)&3 invariant under +64).
  const int r0 = t >> 2;                                   // 0..63
  const int js = ((t & 3) ^ ((r0 >> 1) & 3)) * 16;
  const uint8_t* sA = cq + (size_t)(cb0 + r0) * DIM + js;
  const uint8_t* sB = xq + (size_t)(tb0 + r0) * DIM + js;

#define STAGE(bi, ti) do {                                           \
    uint8_t* Ad_ = smem + ((bi) << 15);                              \
    const int ko_ = (ti) * BK;                                       \
    GLD16(sA + ko_,                 Ad_ + t * 16);                   \
    GLD16(sA + 64 * DIM + ko_,      Ad_ + t * 16 + 4096);            \
    GLD16(sA + 128 * DIM + ko_,     Ad_ + t * 16 + 8192);            \
    GLD16(sA + 192 * DIM + ko_,     Ad_ + t * 16 + 12288);           \
    GLD16(sB + ko_,                 Ad_ + 16384 + t * 16);           \
    GLD16(sB + 64 * DIM + ko_,      Ad_ + 16384 + t * 16 + 4096);    \
    GLD16(sB + 128 * DIM + ko_,     Ad_ + 16384 + t * 16 + 8192);    \
    GLD16(sB + 192 * DIM + ko_,     Ad_ + 16384 + t * 16 + 12288);   \
  } while (0)

  // ds_read offsets: fragment row, source k-chunks {2*hi, 2*hi+1} at slots
  // XOR'd with perm(row). Byte offsets within a 32KB buffer.
  const int j0 = hi * 2;
  int aoff[4][2], boff[4][2];
#pragma unroll
  for (int mi = 0; mi < 4; ++mi) {
    const int ra = wm * 128 + mi * 32 + col;
    const int pa = (ra >> 1) & 3;
    aoff[mi][0] = ra * 64 + (j0 ^ pa) * 16;
    aoff[mi][1] = ra * 64 + ((j0 + 1) ^ pa) * 16;
    const int rb = wn * 128 + mi * 32 + col;
    const int pb = (rb >> 1) & 3;
    boff[mi][0] = 16384 + rb * 64 + (j0 ^ pb) * 16;
    boff[mi][1] = 16384 + rb * 64 + ((j0 + 1) ^ pb) * 16;
  }

  // concat two 16B loads into one 32B fragment (no element-insert movs)
#define READ8(dst_, o0_, o1_) do {                                         \
    const int4v lo_ = *(const int4v*)(cur + (o0_));                        \
    const int4v hq_ = *(const int4v*)(cur + (o1_));                        \
    dst_ = __builtin_shufflevector(lo_, hq_, 0, 1, 2, 3, 4, 5, 6, 7);      \
  } while (0)

  f32x16 acc[4][4];
#pragma unroll
  for (int i = 0; i < 4; ++i)
#pragma unroll
    for (int j = 0; j < 4; ++j)
#pragma unroll
      for (int r = 0; r < 16; ++r) acc[i][j][r] = 0.f;

  // prologue: tiles 0,1 staged (16 GLDs outstanding)
  STAGE(0, 0);
  STAGE(1, 1);

#pragma unroll
  for (int kt = 0; kt < KITERS; ++kt) {
    // tile boundary: counted wait. Steady state outstanding = stage(kt+1)'s 8
    // -> vmcnt(8) guarantees stage(kt) landed without draining the prefetch.
    // Last tile: no newer stage -> vmcnt(0).
    if (kt == KITERS - 1) asm volatile("s_waitcnt vmcnt(0)" ::: "memory");
    else                  asm volatile("s_waitcnt vmcnt(8)" ::: "memory");
    __builtin_amdgcn_s_barrier();
    __builtin_amdgcn_sched_barrier(0);

    const uint8_t* cur = smem + ((kt & 3) << 15);

    // stage tile kt+2 two tiles ahead (compile-time guarded, no wrap stages)
    if (kt < KITERS - 2) STAGE((kt + 2) & 3, kt + 2);

    // 16 ds_read_b128 + 16 MFMA, compiler-scheduled: partial lgkmcnt lets
    // MFMAs start as fragments land; MFMA issue doesn't block the wave, so
    // remaining ds_reads issue under the matrix pipe.
    int8v b[4];
#pragma unroll
    for (int nj = 0; nj < 4; ++nj) READ8(b[nj], boff[nj][0], boff[nj][1]);
#pragma unroll
    for (int mi = 0; mi < 4; ++mi) {
      int8v a;
      READ8(a, aoff[mi][0], aoff[mi][1]);
      acc[mi][0] = MFMA8(a, b[0], acc[mi][0]);
      acc[mi][1] = MFMA8(a, b[1], acc[mi][1]);
      acc[mi][2] = MFMA8(a, b[2], acc[mi][2]);
      acc[mi][3] = MFMA8(a, b[3], acc[mi][3]);
    }
  }
  __syncthreads();   // full drain before smem reuse

  // Epilogue: per-token top-3 over this block's 256 codes.
  // C/D 32x32 layout: col(token)=lane&31, row(code)=(reg&3)+8*(reg>>2)+4*(lane>>5).
  // key = (monotone(value) & ~0xFF) | (255 - code_in_block).
  uint32_t* cand = (uint32_t*)smem;  // [256 tokens][2 wm-halves][3] = 6KB
  const int invb = 255 - wm * 128 - 4 * hi;
#pragma unroll
  for (int nj = 0; nj < 4; ++nj) {
    uint32_t K1 = 0, K2 = 0, K3 = 0;
#pragma unroll
    for (int mi = 0; mi < 4; ++mi) {
#pragma unroll
      for (int rg = 0; rg < 16; ++rg) {
        const int rowoff = (rg & 3) + 8 * (rg >> 2);
        const uint32_t key = (f32_key(acc[mi][nj][rg]) & 0xFFFFFF00u)
                           | (uint32_t)(invb - mi * 32 - rowoff);
        const uint32_t t3 = umed3(key, K2, K3);
        const uint32_t t2 = umed3(key, K1, K2);
        K1 = umax(key, K1); K2 = t2; K3 = t3;
      }
    }
    // merge row-halves (lane ^ 32 holds same token, other 4-row offset)
    const uint32_t o1 = __shfl_xor(K1, 32, 64);
    const uint32_t o2 = __shfl_xor(K2, 32, 64);
    const uint32_t o3 = __shfl_xor(K3, 32, 64);
    const uint32_t m1 = umin(K1, o1), M2 = umax(K2, o2);
    const uint32_t m2 = umin(K2, o2), M3 = umax(K3, o3);
    K1 = umax(K1, o1);
    const uint32_t nk2 = umax(m1, M2);
    K3 = umax(umax(m2, umin(m1, M2)), M3);
    K2 = nk2;
    if (hi == 0) {
      uint32_t* c = &cand[((wn * 128 + nj * 32 + col) * 2 + wm) * 3];
      c[0] = K1; c[1] = K2; c[2] = K3;
    }
  }
  __syncthreads();
  {
    const uint32_t a1 = cand[(t * 2 + 0) * 3 + 0], a2 = cand[(t * 2 + 0) * 3 + 1],
                   a3 = cand[(t * 2 + 0) * 3 + 2];
    const uint32_t b1k = cand[(t * 2 + 1) * 3 + 0], b2 = cand[(t * 2 + 1) * 3 + 1],
                   b3 = cand[(t * 2 + 1) * 3 + 2];
    const uint32_t m1 = umin(a1, b1k), M2 = umax(a2, b2);
    const uint32_t m2 = umin(a2, b2), M3 = umax(a3, b3);
    uint32_t* dst = pk + ((size_t)(tb0 + t) * NBLK + cyi) * 3;
    dst[0] = umax(a1, b1k);
    dst[1] = umax(m1, M2);
    dst[2] = umax(umax(m2, umin(m1, M2)), M3);
  }
#undef STAGE
#undef READ8
}

// ------------------------------------------- reduce + fp64 recheck + gather
__global__ __launch_bounds__(256) void vq_reduce_gather(
    const uint32_t* __restrict__ pk, const float* __restrict__ x,
    const float* __restrict__ cb, float* __restrict__ out)
{
  __shared__ float xs[DIM];
  __shared__ uint32_t wmax[4];
  __shared__ int scand[MAXCAND];
  __shared__ int scnt;
  __shared__ double sdot[MAXCAND];
  __shared__ int sbesti;

  const int tkn = blockIdx.x, t = threadIdx.x, lane = t & 63, wv = t >> 6;
  ((float4*)xs)[t] = ((const float4*)(x + (size_t)tkn * DIM))[t];
  const uint32_t key = (t < 3 * NBLK) ? pk[(size_t)tkn * (3 * NBLK) + t] : 0u;
  uint32_t m = key;
#pragma unroll
  for (int d = 1; d < 64; d <<= 1) m = umax(m, __shfl_xor(m, d, 64));
  if (t == 0) scnt = 0;
  if (lane == 0) wmax[wv] = m;
  __syncthreads();
  const float Mv = key_f32(umax(umax(wmax[0], wmax[1]), umax(wmax[2], wmax[3])));
  if (t < 3 * NBLK && key_f32(key) >= Mv - EPS) {
    const int p = atomicAdd(&scnt, 1);
    if (p < MAXCAND) scand[p] = (t / 3) * BM + 255 - (int)(key & 255u);
  }
  __syncthreads();
  const int cnt = scnt < MAXCAND ? scnt : MAXCAND;

  if (cnt > 1) {
    // wave-parallel: wave wv handles candidates wv, wv+4, ...
    for (int k = wv; k < cnt; k += 4) {
      const int c = scand[k];
      const float* cr = cb + (size_t)c * DIM;
      double s = 0.0;
#pragma unroll
      for (int q = 0; q < 4; ++q) {
        const float4 xv = ((const float4*)xs)[lane + 64 * q];
        const float4 cv = ((const float4*)cr)[lane + 64 * q];
        s += (double)xv.x * cv.x + (double)xv.y * cv.y
           + (double)xv.z * cv.z + (double)xv.w * cv.w;
      }
#pragma unroll
      for (int d = 1; d < 64; d <<= 1) s += __shfl_xor(s, d, 64);
      if (lane == 0) sdot[k] = s;
    }
    __syncthreads();
    if (t == 0) {
      double best = -1e300; int bi = N_CODES;
      for (int k = 0; k < cnt; ++k) {
        const int c = scand[k];
        if (sdot[k] > best || (sdot[k] == best && c < bi)) { best = sdot[k]; bi = c; }
      }
      sbesti = bi;
    }
  } else {
    if (t == 0) sbesti = scand[0];
  }
  __syncthreads();
  const int code = sbesti;
  ((float4*)(out + (size_t)tkn * DIM))[t] = ((const float4*)(cb + (size_t)code * DIM))[t];
}

// ------------------------------------------------- fallback (ws too small)
__global__ __launch_bounds__(256) void vq_naive(const float* __restrict__ x,
                                                const float* __restrict__ cb,
                                                float* __restrict__ out) {
  __shared__ float xs[DIM];
  __shared__ float bv[256];
  __shared__ int   bix[256];
  const int tkn = blockIdx.x;
  const int t = threadIdx.x;
  for (int d = t; d < DIM; d += 256) xs[d] = x[(size_t)tkn * DIM + d];
  __syncthreads();
  float best = -1e30f; int bi = N_CODES;
  for (int c = t; c < N_CODES; c += 256) {
    const float* cr = cb + (size_t)c * DIM;
    float s = 0.f;
    for (int d = 0; d < DIM; ++d) s += xs[d] * cr[d];
    if (s > best || (s == best && c < bi)) { best = s; bi = c; }
  }
  bv[t] = best; bix[t] = bi;
  __syncthreads();
  for (int off = 128; off > 0; off >>= 1) {
    if (t < off) {
      if (bv[t + off] > bv[t] || (bv[t + off] == bv[t] && bix[t + off] < bix[t])) {
        bv[t] = bv[t + off]; bix[t] = bix[t + off];
      }
    }
    __syncthreads();
  }
  const int code = bix[0];
  for (int d = t; d < DIM; d += 256)
    out[(size_t)tkn * DIM + d] = cb[(size_t)code * DIM + d];
}

// ---------------------------------------------------------------------- launch
extern "C" void kernel_launch(void* const* d_in, const int* in_sizes, int n_in,
                              void* d_out, int out_size, void* d_ws, size_t ws_size,
                              hipStream_t stream) {
  const float* x  = (const float*)d_in[0];   // [16384][1024]
  const float* cb = (const float*)d_in[1];   // [8192][1024]
  float* out = (float*)d_out;

  const size_t MB = 1024 * 1024;
  const size_t need = 24 * MB + (size_t)T_TOKENS * NBLK * 3 * 4;  // ~30.3MB
  if (ws_size >= need) {
    uint8_t*  xq = (uint8_t*)d_ws;             // 16MB fp8 tokens
    uint8_t*  cq = xq + 16 * MB;               // 8MB  fp8 codebook
    uint32_t* pk = (uint32_t*)(cq + 8 * MB);   // 6.3MB packed keys

    vq_prep<<<dim3(24576), 256, 0, stream>>>(x, cb, xq, cq);
    vq_gemm_top3<<<dim3((T_TOKENS / BN) * (N_CODES / BM)), 256, 0, stream>>>(cq, xq, pk);
    vq_reduce_gather<<<dim3(T_TOKENS), 256, 0, stream>>>(pk, x, cb, out);
  } else {
    vq_naive<<<dim3(T_TOKENS), 256, 0, stream>>>(x, cb, out);
  }
}